// Round 1
// baseline (121.053 us; speedup 1.0000x reference)
//
#include <hip/hip_runtime.h>
#include <stdint.h>

// Problem constants (fixed by the reference):
#define B 16
#define C 64
#define N 65536   // 256*256 positions
#define K 64

// ---------------------------------------------------------------------------
// Kernel 1: powsum[b][n] = sum_c x[b][c][n]^2
// Grid: B*64 blocks of 256 threads; each thread handles 4 consecutive n via
// float4 (16B/lane coalesced). Reads 256 MiB once -> HBM-bound.
// ---------------------------------------------------------------------------
__global__ __launch_bounds__(256) void powsum_kernel(const float* __restrict__ x,
                                                     float* __restrict__ ps) {
    const int b   = blockIdx.x >> 6;    // 64 blocks per batch
    const int blk = blockIdx.x & 63;
    const int n4  = blk * 1024 + threadIdx.x * 4;   // 256 threads * 4 = 1024 pos/block

    const float4* xp = (const float4*)(x + (size_t)b * C * N + n4);
    float4 acc = {0.f, 0.f, 0.f, 0.f};
    #pragma unroll 8
    for (int c = 0; c < C; ++c) {
        float4 v = xp[(size_t)c * (N / 4)];
        acc.x += v.x * v.x;
        acc.y += v.y * v.y;
        acc.z += v.z * v.z;
        acc.w += v.w * v.w;
    }
    *(float4*)(ps + (size_t)b * N + n4) = acc;
}

// ---------------------------------------------------------------------------
// Kernel 2: per-batch exact top-K by radix select on the f32 bit pattern
// (powsum >= 0 so uint32 order == float order). One 1024-thread block per
// batch. Phases: 11-bit / 11-bit / 10-bit histograms -> exact threshold T,
// then collect (v > T) plus lowest-index ties (v == T), rank-sort 64 winners
// by (value desc, idx asc), and gather the output rows (fused).
// ---------------------------------------------------------------------------
#define NB1   2048
#define EQCAP 1024

__global__ __launch_bounds__(1024) void topk_kernel(const float* __restrict__ x,
                                                    const float* __restrict__ ps,
                                                    float* __restrict__ out) {
    const int b   = blockIdx.x;
    const int tid = threadIdx.x;
    const uint32_t* bits = (const uint32_t*)(ps + (size_t)b * N);

    __shared__ uint32_t hist[NB1];
    __shared__ uint32_t sh_bin, sh_ngt;
    __shared__ uint32_t sel_idx[K];
    __shared__ uint32_t s_vals[K], s_idx[K];
    __shared__ uint32_t eq_idx[EQCAP];
    __shared__ uint32_t sel_cnt, eq_cnt;

    uint32_t kneed   = K;   // how many still needed (same value in every thread)
    uint32_t selbits = 0;   // bin path chosen so far

    // ---- 3 radix phases ----------------------------------------------------
    for (int phase = 0; phase < 3; ++phase) {
        hist[tid] = 0u; hist[tid + 1024] = 0u;
        __syncthreads();

        for (int i = tid; i < N; i += 1024) {
            uint32_t v = bits[i];
            uint32_t binv; bool ok;
            if (phase == 0)      { binv = v >> 21;          ok = true; }
            else if (phase == 1) { binv = (v >> 10) & 0x7FFu; ok = ((v >> 21) == selbits); }
            else                 { binv = v & 0x3FFu;        ok = ((v >> 10) == selbits); }
            if (ok) atomicAdd(&hist[binv], 1u);
        }
        __syncthreads();

        // inclusive suffix scan over 2048 bins (Hillis-Steele, 2 elems/thread)
        for (int off = 1; off < NB1; off <<= 1) {
            const int i0 = tid, i1 = tid + 1024;
            uint32_t a0 = hist[i0] + ((i0 + off < NB1) ? hist[i0 + off] : 0u);
            uint32_t a1 = hist[i1] + ((i1 + off < NB1) ? hist[i1 + off] : 0u);
            __syncthreads();
            hist[i0] = a0; hist[i1] = a1;
            __syncthreads();
        }

        // find largest bin j with suffix_count(j) >= kneed (hist non-increasing)
        for (int j = tid; j < NB1; j += 1024) {
            uint32_t ge  = hist[j];
            uint32_t gen = (j + 1 < NB1) ? hist[j + 1] : 0u;
            if (ge >= kneed && gen < kneed) { sh_bin = (uint32_t)j; sh_ngt = gen; }
        }
        __syncthreads();

        if (phase == 0)      selbits = sh_bin;
        else if (phase == 1) selbits = (selbits << 11) | sh_bin;
        else                 selbits = (selbits << 10) | sh_bin;
        kneed -= sh_ngt;     // subtract count of strictly-greater values found
        __syncthreads();
    }

    const uint32_t T       = selbits;   // exact K-th largest value (bits)
    const uint32_t need_eq = kneed;     // how many ties at == T to take (>= 1)

    // ---- collection --------------------------------------------------------
    if (tid == 0) { sel_cnt = 0u; eq_cnt = 0u; }
    __syncthreads();
    for (int i = tid; i < N; i += 1024) {
        uint32_t v = bits[i];
        if (v > T) {
            uint32_t p = atomicAdd(&sel_cnt, 1u);
            sel_idx[p] = (uint32_t)i;               // exactly K - need_eq of these
        } else if (v == T) {
            uint32_t p = atomicAdd(&eq_cnt, 1u);
            if (p < EQCAP) eq_idx[p] = (uint32_t)i; // ties (typically 1)
        }
    }
    __syncthreads();

    const uint32_t ngt = sel_cnt;                   // == K - need_eq
    const uint32_t m   = (eq_cnt < EQCAP) ? eq_cnt : EQCAP;
    // take the need_eq smallest-index ties (rank by index)
    for (uint32_t t = tid; t < m; t += 1024) {
        uint32_t my = eq_idx[t];
        uint32_t r  = 0;
        for (uint32_t j = 0; j < m; ++j) r += (eq_idx[j] < my) ? 1u : 0u;
        if (r < need_eq) sel_idx[ngt + r] = my;
    }
    __syncthreads();

    // ---- rank-sort the K winners by (value desc, index asc) ----------------
    if (tid < K) {
        uint32_t idx = sel_idx[tid];
        s_vals[tid] = bits[idx];
        s_idx[tid]  = idx;
    }
    __syncthreads();
    if (tid < K) {
        uint32_t v = s_vals[tid], id = s_idx[tid];
        int r = 0;
        for (int j = 0; j < K; ++j) {
            uint32_t vj = s_vals[j], ij = s_idx[j];
            if (vj > v || (vj == v && ij < id)) ++r;
        }
        sel_idx[r] = id;   // reuse sel_idx as the sorted index list
    }
    __syncthreads();

    // ---- fused gather: out[b][k][c] = x[b][c][n_k] -------------------------
    const int c = tid & 63;
    for (int k = tid >> 6; k < K; k += 16) {
        uint32_t n = sel_idx[k];
        out[((size_t)b * K + k) * C + c] = x[((size_t)b * C + c) * N + n];
    }
}

// ---------------------------------------------------------------------------
extern "C" void kernel_launch(void* const* d_in, const int* in_sizes, int n_in,
                              void* d_out, int out_size, void* d_ws, size_t ws_size,
                              hipStream_t stream) {
    const float* x  = (const float*)d_in[0];
    float*       out = (float*)d_out;
    float*       ps  = (float*)d_ws;    // B*N floats = 4 MiB scratch

    powsum_kernel<<<dim3(B * 64), dim3(256), 0, stream>>>(x, ps);
    topk_kernel<<<dim3(B), dim3(1024), 0, stream>>>(x, ps, out);
}

// Round 2
// 87.172 us; speedup vs baseline: 1.3887x; 1.3887x over previous
//
#include <hip/hip_runtime.h>
#include <stdint.h>

// Problem constants (fixed by the reference):
#define B 16
#define C 64
#define N 65536   // 256*256 positions
#define K 64

#define NBINS 8192   // top-13 bits of a positive f32 (0|exp8|mant4): ~4.5% bin width
#define CAP   4096   // candidate capacity per batch (expected ~250 for chi^2(64) tail)

// ws layout: ps = B*N f32 (4 MiB) | ghist = B*NBINS u32 (512 KiB)

// ---------------------------------------------------------------------------
// Kernel 1: powsum[b][n] = sum_c x[b][c][n]^2, plus per-batch global histogram
// of the top-13 bits (per-block LDS histogram -> sparse global atomic merge).
// 1024 blocks x 256 threads, float4 per lane -> HBM-bound stream of 256 MiB.
// ---------------------------------------------------------------------------
__global__ __launch_bounds__(256) void powsum_hist_kernel(const float* __restrict__ x,
                                                          float* __restrict__ ps,
                                                          uint32_t* __restrict__ ghist) {
    __shared__ uint32_t lh[NBINS];   // 32 KiB
    const int b   = blockIdx.x >> 6;    // 64 blocks per batch
    const int blk = blockIdx.x & 63;
    const int n4  = blk * 1024 + threadIdx.x * 4;

    for (int j = threadIdx.x; j < NBINS; j += 256) lh[j] = 0u;
    __syncthreads();

    const float4* xp = (const float4*)(x + (size_t)b * C * N + n4);
    float4 acc = {0.f, 0.f, 0.f, 0.f};
    #pragma unroll 8
    for (int c = 0; c < C; ++c) {
        float4 v = xp[(size_t)c * (N / 4)];
        acc.x += v.x * v.x;
        acc.y += v.y * v.y;
        acc.z += v.z * v.z;
        acc.w += v.w * v.w;
    }
    *(float4*)(ps + (size_t)b * N + n4) = acc;

    const uint4 ub = *(const uint4*)&acc;       // powsum >= 0: uint order == float order
    atomicAdd(&lh[ub.x >> 19], 1u);
    atomicAdd(&lh[ub.y >> 19], 1u);
    atomicAdd(&lh[ub.z >> 19], 1u);
    atomicAdd(&lh[ub.w >> 19], 1u);
    __syncthreads();

    uint32_t* gh = ghist + (size_t)b * NBINS;
    for (int j = threadIdx.x; j < NBINS; j += 256) {
        uint32_t c = lh[j];
        if (c) atomicAdd(&gh[j], c);            // ~50 nonzero bins per block
    }
}

// ---------------------------------------------------------------------------
// Kernel 2: per-batch (16 blocks x 1024 threads)
//   1) suffix-scan the 8192-bin histogram -> threshold bin binT
//   2) collect candidates with bin >= binT (expected ~250)
//   3) exact rank-sort by (value desc, idx asc)  == lax.top_k order
//   4) fused gather of the 64 selected rows
// ---------------------------------------------------------------------------
__global__ __launch_bounds__(1024) void select_kernel(const float* __restrict__ x,
                                                      const float* __restrict__ ps,
                                                      const uint32_t* __restrict__ ghist,
                                                      float* __restrict__ out) {
    const int b   = blockIdx.x;
    const int tid = threadIdx.x;

    __shared__ uint32_t csum[1024];
    __shared__ uint32_t sh_binT;
    __shared__ uint32_t cand_v[CAP], cand_i[CAP];   // 32 KiB
    __shared__ uint32_t cnt;
    __shared__ uint32_t sel[K];

    // ---- 1) threshold bin from histogram -----------------------------------
    const uint32_t* gh = ghist + (size_t)b * NBINS;
    uint32_t h[8];
    #pragma unroll
    for (int j = 0; j < 8; ++j) h[j] = gh[tid * 8 + j];
    uint32_t s = 0;
    #pragma unroll
    for (int j = 0; j < 8; ++j) s += h[j];
    csum[tid] = s;
    __syncthreads();
    // inclusive suffix scan over 1024 chunk sums (Hillis-Steele)
    for (int off = 1; off < 1024; off <<= 1) {
        uint32_t v = csum[tid] + ((tid + off < 1024) ? csum[tid + off] : 0u);
        __syncthreads();
        csum[tid] = v;
        __syncthreads();
    }
    const uint32_t nxt = (tid < 1023) ? csum[tid + 1] : 0u;
    uint32_t ls[9];
    ls[8] = nxt;
    #pragma unroll
    for (int j = 7; j >= 0; --j) ls[j] = ls[j + 1] + h[j];
    // crossing: suffix(bin) >= K and suffix(bin+1) < K  (exactly one exists)
    #pragma unroll
    for (int j = 0; j < 8; ++j) {
        if (ls[j] >= K && ls[j + 1] < K) sh_binT = (uint32_t)(tid * 8 + j);
    }
    if (tid == 0) cnt = 0u;
    __syncthreads();
    const uint32_t binT = sh_binT;

    // ---- 2) collect candidates --------------------------------------------
    const uint32_t* bits = (const uint32_t*)(ps + (size_t)b * N);
    for (int i = tid; i < N; i += 1024) {
        uint32_t v = bits[i];
        if ((v >> 19) >= binT) {
            uint32_t p = atomicAdd(&cnt, 1u);
            if (p < CAP) { cand_v[p] = v; cand_i[p] = (uint32_t)i; }
        }
    }
    __syncthreads();
    const uint32_t M = (cnt < (uint32_t)CAP) ? cnt : (uint32_t)CAP;

    // ---- 3) exact rank sort (value desc, idx asc) -------------------------
    for (uint32_t t = tid; t < M; t += 1024) {
        const uint32_t v = cand_v[t], id = cand_i[t];
        uint32_t r = 0;
        for (uint32_t j = 0; j < M; ++j) {       // LDS broadcast reads
            const uint32_t vj = cand_v[j], ij = cand_i[j];
            r += (vj > v || (vj == v && ij < id)) ? 1u : 0u;
        }
        if (r < K) sel[r] = id;
    }
    __syncthreads();

    // ---- 4) fused gather: out[b][k][c] = x[b][c][n_k] ---------------------
    const int c = tid & 63;
    for (int k = tid >> 6; k < K; k += 16) {
        const uint32_t n = sel[k];
        out[((size_t)b * K + k) * C + c] = x[((size_t)b * C + c) * N + n];
    }
}

// ---------------------------------------------------------------------------
extern "C" void kernel_launch(void* const* d_in, const int* in_sizes, int n_in,
                              void* d_out, int out_size, void* d_ws, size_t ws_size,
                              hipStream_t stream) {
    const float* x   = (const float*)d_in[0];
    float*       out = (float*)d_out;
    float*       ps  = (float*)d_ws;
    uint32_t*    ghist = (uint32_t*)((char*)d_ws + (size_t)B * N * sizeof(float));

    hipMemsetAsync(ghist, 0, (size_t)B * NBINS * sizeof(uint32_t), stream);
    powsum_hist_kernel<<<dim3(B * 64), dim3(256), 0, stream>>>(x, ps, ghist);
    select_kernel<<<dim3(B), dim3(1024), 0, stream>>>(x, ps, ghist, out);
}

// Round 3
// 80.659 us; speedup vs baseline: 1.5008x; 1.0807x over previous
//
#include <hip/hip_runtime.h>
#include <stdint.h>

// Problem constants (fixed by the reference):
#define B 16
#define C 64
#define N 65536   // 256*256 positions
#define K 64

#define NBINS 4096   // bits>>19 of a positive f32: exp(8)+mant(4) in [0,4096)
#define CAP   4096   // candidate capacity per batch (expected ~250 for chi^2(64) tail)

// ws layout:
//   ps     : B*N f32          = 4 MiB    (offset 0)
//   ghist  : B*NBINS u32      = 256 KiB
//   cnt    : B u32 (pad 256B)
//   cand_v : B*CAP u32        = 256 KiB
//   cand_i : B*CAP u32        = 256 KiB
#define PS_OFF    0
#define GH_OFF    ((size_t)B * N * sizeof(float))
#define CNT_OFF   (GH_OFF + (size_t)B * NBINS * sizeof(uint32_t))
#define CV_OFF    (CNT_OFF + 256)
#define CI_OFF    (CV_OFF + (size_t)B * CAP * sizeof(uint32_t))

// ---------------------------------------------------------------------------
// Kernel 1: powsum[b][n] = sum_c x[b][c][n]^2, plus per-batch histogram of the
// top-12 bits (per-block LDS histogram -> sparse global atomic merge).
// 1024 blocks x 256 threads, float4 per lane -> HBM-bound stream of 256 MiB.
// ---------------------------------------------------------------------------
__global__ __launch_bounds__(256) void powsum_hist_kernel(const float* __restrict__ x,
                                                          float* __restrict__ ps,
                                                          uint32_t* __restrict__ ghist) {
    __shared__ uint32_t lh[NBINS];   // 16 KiB -> 8 blocks/CU (wave-slot limited)
    const int b   = blockIdx.x >> 6;    // 64 blocks per batch
    const int blk = blockIdx.x & 63;
    const int n4  = blk * 1024 + threadIdx.x * 4;

    for (int j = threadIdx.x; j < NBINS; j += 256) lh[j] = 0u;
    __syncthreads();

    const float4* xp = (const float4*)(x + (size_t)b * C * N + n4);
    float4 acc = {0.f, 0.f, 0.f, 0.f};
    #pragma unroll 8
    for (int c = 0; c < C; ++c) {
        float4 v = xp[(size_t)c * (N / 4)];
        acc.x += v.x * v.x;
        acc.y += v.y * v.y;
        acc.z += v.z * v.z;
        acc.w += v.w * v.w;
    }
    *(float4*)(ps + (size_t)b * N + n4) = acc;

    const uint4 ub = *(const uint4*)&acc;       // powsum >= 0: uint order == float order
    atomicAdd(&lh[ub.x >> 19], 1u);
    atomicAdd(&lh[ub.y >> 19], 1u);
    atomicAdd(&lh[ub.z >> 19], 1u);
    atomicAdd(&lh[ub.w >> 19], 1u);
    __syncthreads();

    uint32_t* gh = ghist + (size_t)b * NBINS;
    for (int j = threadIdx.x; j < NBINS; j += 256) {
        uint32_t c = lh[j];
        if (c) atomicAdd(&gh[j], c);            // ~50 nonzero bins per block
    }
}

// ---------------------------------------------------------------------------
// Kernel 2: 1024 blocks x 256 threads (same geometry as k1).
// Each block: (a) redundantly suffix-scans its batch's 4096-bin histogram
// (L2-resident) to find binT = largest bin with suffix >= K; (b) scans its
// 1024-value chunk of ps, appending candidates (bin >= binT) to the global
// per-batch candidate list.
// ---------------------------------------------------------------------------
__global__ __launch_bounds__(256) void collect_kernel(const float* __restrict__ ps,
                                                      const uint32_t* __restrict__ ghist,
                                                      uint32_t* __restrict__ cnt,
                                                      uint32_t* __restrict__ cand_v,
                                                      uint32_t* __restrict__ cand_i) {
    const int b   = blockIdx.x >> 6;
    const int blk = blockIdx.x & 63;
    const int tid = threadIdx.x;

    __shared__ uint32_t csum[256];
    __shared__ uint32_t sh_binT;

    // ---- (a) threshold bin -------------------------------------------------
    const uint32_t* gh = ghist + (size_t)b * NBINS;
    uint32_t h[16];
    const uint4* gh4 = (const uint4*)(gh + tid * 16);
    #pragma unroll
    for (int j = 0; j < 4; ++j) {
        uint4 t4 = gh4[j];
        h[4*j] = t4.x; h[4*j+1] = t4.y; h[4*j+2] = t4.z; h[4*j+3] = t4.w;
    }
    uint32_t s = 0;
    #pragma unroll
    for (int j = 0; j < 16; ++j) s += h[j];
    csum[tid] = s;
    __syncthreads();
    for (int off = 1; off < 256; off <<= 1) {      // inclusive suffix scan
        uint32_t v = csum[tid] + ((tid + off < 256) ? csum[tid + off] : 0u);
        __syncthreads();
        csum[tid] = v;
        __syncthreads();
    }
    uint32_t ls[17];
    ls[16] = (tid < 255) ? csum[tid + 1] : 0u;
    #pragma unroll
    for (int j = 15; j >= 0; --j) ls[j] = ls[j + 1] + h[j];
    #pragma unroll
    for (int j = 0; j < 16; ++j) {
        if (ls[j] >= K && ls[j + 1] < K) sh_binT = (uint32_t)(tid * 16 + j);
    }
    __syncthreads();
    const uint32_t binT = sh_binT;

    // ---- (b) collect from this block's chunk ------------------------------
    const int n4 = blk * 1024 + tid * 4;
    const uint32_t* bits = (const uint32_t*)(ps + (size_t)b * N);
    uint4 v4 = *(const uint4*)(bits + n4);
    uint32_t vv[4] = {v4.x, v4.y, v4.z, v4.w};
    #pragma unroll
    for (int j = 0; j < 4; ++j) {
        if ((vv[j] >> 19) >= binT) {
            uint32_t p = atomicAdd(&cnt[b], 1u);
            if (p < CAP) {
                cand_v[(size_t)b * CAP + p] = vv[j];
                cand_i[(size_t)b * CAP + p] = (uint32_t)(n4 + j);
            }
        }
    }
}

// ---------------------------------------------------------------------------
// Kernel 3: per-batch (16 blocks x 256 threads) exact rank-sort of candidates
// by (value desc, idx asc) == lax.top_k order, then fused gather.
// Order-independent ranking -> deterministic despite atomic append order.
// ---------------------------------------------------------------------------
__global__ __launch_bounds__(256) void sort_gather_kernel(const float* __restrict__ x,
                                                          const uint32_t* __restrict__ cnt,
                                                          const uint32_t* __restrict__ cand_v,
                                                          const uint32_t* __restrict__ cand_i,
                                                          float* __restrict__ out) {
    const int b   = blockIdx.x;
    const int tid = threadIdx.x;

    __shared__ uint32_t sv[CAP], si[CAP];   // 32 KiB
    __shared__ uint32_t sel[K];

    const uint32_t M = (cnt[b] < (uint32_t)CAP) ? cnt[b] : (uint32_t)CAP;
    for (uint32_t t = tid; t < M; t += 256) {
        sv[t] = cand_v[(size_t)b * CAP + t];
        si[t] = cand_i[(size_t)b * CAP + t];
    }
    __syncthreads();

    for (uint32_t t = tid; t < M; t += 256) {
        const uint32_t v = sv[t], id = si[t];
        uint32_t r = 0;
        for (uint32_t j = 0; j < M; ++j) {          // LDS broadcast reads
            const uint32_t vj = sv[j], ij = si[j];
            r += (vj > v || (vj == v && ij < id)) ? 1u : 0u;
        }
        if (r < K) sel[r] = id;
    }
    __syncthreads();

    // out[b][k][c] = x[b][c][n_k]
    const int c = tid & 63;
    for (int k = tid >> 6; k < K; k += 4) {
        const uint32_t n = sel[k];
        out[((size_t)b * K + k) * C + c] = x[((size_t)b * C + c) * N + n];
    }
}

// ---------------------------------------------------------------------------
extern "C" void kernel_launch(void* const* d_in, const int* in_sizes, int n_in,
                              void* d_out, int out_size, void* d_ws, size_t ws_size,
                              hipStream_t stream) {
    const float* x   = (const float*)d_in[0];
    float*       out = (float*)d_out;
    char*        ws  = (char*)d_ws;

    float*    ps     = (float*)(ws + PS_OFF);
    uint32_t* ghist  = (uint32_t*)(ws + GH_OFF);
    uint32_t* cnt    = (uint32_t*)(ws + CNT_OFF);
    uint32_t* cand_v = (uint32_t*)(ws + CV_OFF);
    uint32_t* cand_i = (uint32_t*)(ws + CI_OFF);

    // zero ghist + cnt in one shot (contiguous region)
    hipMemsetAsync(ghist, 0, (CNT_OFF - GH_OFF) + 256, stream);
    powsum_hist_kernel<<<dim3(B * 64), dim3(256), 0, stream>>>(x, ps, ghist);
    collect_kernel<<<dim3(B * 64), dim3(256), 0, stream>>>(ps, ghist, cnt, cand_v, cand_i);
    sort_gather_kernel<<<dim3(B), dim3(256), 0, stream>>>(x, cnt, cand_v, cand_i, out);
}